// Round 2
// baseline (12713.085 us; speedup 1.0000x reference)
//
#include <hip/hip_runtime.h>

#define B_ 64
#define S_ 2048
#define I_ 512
#define H_ 512

typedef _Float16 half2v __attribute__((ext_vector_type(2)));
typedef _Float16 half8v __attribute__((ext_vector_type(8)));
typedef float    float4v __attribute__((ext_vector_type(4)));
typedef float    float2v __attribute__((ext_vector_type(2)));
typedef unsigned int uint4v __attribute__((ext_vector_type(4)));
typedef unsigned short ushort_t;

__device__ inline unsigned int pk2(float a, float b) {
    // v_cvt_pkrtz_f16_f32: pack (a->low, b->high)
    return __builtin_bit_cast(unsigned int, __builtin_amdgcn_cvt_pkrtz(a, b));
}

__device__ inline uint4v pack8(float4v a, float4v b) {
    uint4v r;
    r.x = pk2(a.x, a.y);
    r.y = pk2(a.z, a.w);
    r.z = pk2(b.x, b.y);
    r.w = pk2(b.z, b.w);
    return r;
}

__device__ inline float fdot2u(unsigned int h2, unsigned int w2, float acc) {
    return __builtin_amdgcn_fdot2(__builtin_bit_cast(half2v, h2),
                                  __builtin_bit_cast(half2v, w2), acc, false);
}

__device__ inline float fast_tanh(float y) {
    // tanh(y) = 1 - 2/(exp2(y*2*log2e) + 1); saturates correctly at +/-inf
    float e = __builtin_amdgcn_exp2f(y * 2.88539008f);
    return 1.f - 2.f * __builtin_amdgcn_rcpf(e + 1.f);
}

// v += dpp_perm(v): ctrl literal. quad_perm xor1=0xB1, row_ror:4=0x124, row_ror:8=0x128
#define DPPADD(v, ctrl)                                                       \
    ((v) + __builtin_bit_cast(float, __builtin_amdgcn_update_dpp(             \
               0, __builtin_bit_cast(int, (v)), (ctrl), 0xf, 0xf, true)))
// pure DPP move (cross-lane permute), ctrl literal
#define DPPMOV(v, ctrl)                                                       \
    (__builtin_bit_cast(float, __builtin_amdgcn_update_dpp(                   \
        0, __builtin_bit_cast(int, (v)), (ctrl), 0xf, 0xf, true)))

// LDS h staging swizzle: logical u32 word w (0..255) -> slot so that a wave's
// 16 distinct (slice, subchunk) b128 reads spread over all 8 bank-groups.
__device__ inline int swz(int w) {
    int sw = w >> 4;                       // slice 0..15
    int i4 = (w >> 2) & 3;                 // 16B sub-chunk
    return sw * 16 + ((i4 ^ ((sw >> 1) & 3)) * 4) + (w & 3);
}

// ---------------------------------------------------------------------------
// Kernel 0: zero the 256 exchange flags in d_ws (re-zeroed every launch).
// ---------------------------------------------------------------------------
__global__ void zero_flags(int* __restrict__ flags) {
    flags[threadIdx.x] = 0;
}

// ---------------------------------------------------------------------------
// Kernel 1: xp[m, n] = sum_k inputs[m, k] * W_ih[n, k] + b_ih[n]
// M = 131072, N = 512, K = 512.  Unchanged (verified, ~470 us).
// ---------------------------------------------------------------------------
__global__ __launch_bounds__(256, 2) void xproj_gemm(
    const float* __restrict__ A,    // [131072, 512] inputs
    const float* __restrict__ Bw,   // [512, 512]    W_ih
    const float* __restrict__ bias, // [512]         b_ih
    float* __restrict__ C)          // [131072, 512] -> d_out
{
    __shared__ uint4v As[64 * 5];
    __shared__ uint4v Bs[512 * 5];

    const int tid  = threadIdx.x;
    const int wave = tid >> 6;
    const int lane = tid & 63;
    const int lm   = lane & 15;
    const int lq   = lane >> 4;
    const int m0   = blockIdx.x * 64;
    const int nb   = wave * 128;

    float4v acc[4][8];
#pragma unroll
    for (int mf = 0; mf < 4; ++mf)
#pragma unroll
        for (int nf = 0; nf < 8; ++nf)
            acc[mf][nf] = (float4v){0.f, 0.f, 0.f, 0.f};

    float biasv[8];
#pragma unroll
    for (int nf = 0; nf < 8; ++nf)
        biasv[nf] = bias[nb + nf * 16 + lm];

    const int sm    = tid >> 2;
    const int skq   = tid & 3;
    const int sslot = skq ^ (sm & 3);

    for (int kt = 0; kt < 16; ++kt) {
        const int k0 = kt * 32;
        const float* ap = A + (size_t)(m0 + sm) * 512 + k0 + skq * 8;
        float4v a0 = *(const float4v*)ap;
        float4v a1 = *(const float4v*)(ap + 4);
        float4v b0[8], b1[8];
#pragma unroll
        for (int i = 0; i < 8; ++i) {
            const float* bp = Bw + (size_t)(sm + 64 * i) * 512 + k0 + skq * 8;
            b0[i] = *(const float4v*)bp;
            b1[i] = *(const float4v*)(bp + 4);
        }
        __syncthreads();
        As[sm * 5 + sslot] = pack8(a0, a1);
#pragma unroll
        for (int i = 0; i < 8; ++i)
            Bs[(sm + 64 * i) * 5 + sslot] = pack8(b0[i], b1[i]);
        __syncthreads();

        half8v af[4];
#pragma unroll
        for (int mf = 0; mf < 4; ++mf) {
            int row = mf * 16 + lm;
            af[mf] = __builtin_bit_cast(half8v, As[row * 5 + (lq ^ (lm & 3))]);
        }
        half8v bfr[8];
#pragma unroll
        for (int nf = 0; nf < 8; ++nf) {
            int row = nb + nf * 16 + lm;
            bfr[nf] = __builtin_bit_cast(half8v, Bs[row * 5 + (lq ^ (lm & 3))]);
        }
#pragma unroll
        for (int mf = 0; mf < 4; ++mf)
#pragma unroll
            for (int nf = 0; nf < 8; ++nf)
                acc[mf][nf] = __builtin_amdgcn_mfma_f32_16x16x32_f16(
                    af[mf], bfr[nf], acc[mf][nf], 0, 0, 0);
    }

#pragma unroll
    for (int mf = 0; mf < 4; ++mf) {
        int mrow = m0 + mf * 16 + lq * 4;
#pragma unroll
        for (int nf = 0; nf < 8; ++nf) {
            float* cp = C + (size_t)mrow * 512 + nb + nf * 16 + lm;
            float4v v = acc[mf][nf];
            cp[0]    = v.x + biasv[nf];
            cp[512]  = v.y + biasv[nf];
            cp[1024] = v.z + biasv[nf];
            cp[1536] = v.w + biasv[nf];
        }
    }
}

// ---------------------------------------------------------------------------
// Kernel 2 (RESTRUCTURED): 4 workgroups per batch, W truly register-resident.
//
// Grid 256 = 64 batches x 4 j-chunks (bid = c*64 + b: all 4 chunks of batch b
// share bid%8 -> same XCD under round-robin placement, cheap flag exchange).
// 512 threads/WG, __launch_bounds__(512,1) -> 8 waves/CU -> 256-VGPR cap:
// W slice = 128 rows x 512 cols fp16 = 512 thr x 64 u32 VGPRs (~110 total
// VGPRs used -> NO spill, unlike rounds 0/1 whose VGPR_Count=64 betrayed
// scratch/AGPR-resident W reloaded 512 KB/CU/step).
//
// Lane decomposition (l = lane): jlo=l&3, kh=(l>>2)&3, jhi=l>>4; own output
// j = c*128 + w8*16 + jhi*4 + jlo; k-slice s = kh*4+jlo covers halves
// [s*32, s*32+32).  Per step:
//   - 4x ds_read_b128 of own h slice (swizzled layout, 2-way banks = free)
//   - 4 phases x 16 fdot2: the quad's 4 outputs' accumulators ROTATE through
//     the quad (1 DPP mov/phase); W regs pre-permuted at load so every
//     register index is compile-time (no scratch).
//   - kh-reduce: acc += row_ror:4 + row_ror:8 (stride-4 class sum).
//   - h_t published through the `out` array itself (required output anyway)
//     with agent-scope relaxed atomics; one release/acquire flag per WG/step.
//   - xp for own j prefetched 2 steps ahead (own chunk never written by peers).
// ---------------------------------------------------------------------------
__global__ __launch_bounds__(512, 1) void rnn_scan4(
    const float* __restrict__ h0,   // [64, 512]
    const float* __restrict__ Whh,  // [512, 512]
    const float* __restrict__ bhh,  // [512]
    float* __restrict__ out,        // [B*S*H + B*H]
    int* __restrict__ flags)        // [256] in d_ws, zeroed per launch
{
    __shared__ unsigned int hw[2 * 256];   // h double buffer, packed fp16, swizzled

    const int tid = threadIdx.x;
    const int l   = tid & 63;
    const int w8  = tid >> 6;       // wave 0..7
    const int jlo = l & 3;
    const int kh  = (l >> 2) & 3;
    const int jhi = l >> 4;
    const int bid = blockIdx.x;
    const int b   = bid & 63;
    const int c   = bid >> 6;       // j-chunk 0..3

    const int jloc = w8 * 16 + jhi * 4;          // local row base (add jlo)
    const int jg   = c * 128 + jloc + jlo;       // own global j
    const int s    = kh * 4 + jlo;               // k-slice 0..15
    const int X    = (s >> 1) & 3;               // staging swizzle constant

    // --- W fragments, pre-permuted for the acc-rotation schedule ---
    // wv[p][i].m = packed pair W[rp][col..col+1],
    //   rp  = c*128 + jloc + ((jlo+p)&3),  col = s*32 + (i^X)*8 + 2m
    uint4v wv[4][4];
#pragma unroll
    for (int p = 0; p < 4; ++p) {
        const float* wr =
            Whh + (size_t)(c * 128 + jloc + ((jlo + p) & 3)) * 512 + s * 32;
#pragma unroll
        for (int i = 0; i < 4; ++i) {
            const float* wp = wr + (i ^ X) * 8;
            float4v f0 = *(const float4v*)wp;
            float4v f1 = *(const float4v*)(wp + 4);
            wv[p][i] = pack8(f0, f1);
        }
    }

    float* outb = out + (size_t)b * (S_ * H_);
    const float bj = bhh[jg];
    float xpA = outb[jg];          // xp t=0 (all lanes; 4x kh-redundant, fine)
    float xpB = outb[H_ + jg];     // xp t=1

    // stage h_{-1} = h0 into buffer 0 (packed fp16, swizzled)
    if (tid < 256) {
        float f0 = h0[b * 512 + 2 * tid];
        float f1 = h0[b * 512 + 2 * tid + 1];
        hw[swz(tid)] = pk2(f0, f1);
    }
    __syncthreads();

    for (int t = 0; t < S_; ++t) {
        // --- own h slice: 4x b128, conflict-free tier ---
        const uint4v* hb = (const uint4v*)(hw + (t & 1) * 256);
        uint4v t0 = hb[s * 4 + 0];
        uint4v t1 = hb[s * 4 + 1];
        uint4v t2 = hb[s * 4 + 2];
        uint4v t3 = hb[s * 4 + 3];

        // --- 4 phases, rotating accumulator through the quad ---
        float acc = 0.f;
#pragma unroll
        for (int p = 0; p < 4; ++p) {
            acc = fdot2u(t0.x, wv[p][0].x, acc);
            acc = fdot2u(t0.y, wv[p][0].y, acc);
            acc = fdot2u(t0.z, wv[p][0].z, acc);
            acc = fdot2u(t0.w, wv[p][0].w, acc);
            acc = fdot2u(t1.x, wv[p][1].x, acc);
            acc = fdot2u(t1.y, wv[p][1].y, acc);
            acc = fdot2u(t1.z, wv[p][1].z, acc);
            acc = fdot2u(t1.w, wv[p][1].w, acc);
            acc = fdot2u(t2.x, wv[p][2].x, acc);
            acc = fdot2u(t2.y, wv[p][2].y, acc);
            acc = fdot2u(t2.z, wv[p][2].z, acc);
            acc = fdot2u(t2.w, wv[p][2].w, acc);
            acc = fdot2u(t3.x, wv[p][3].x, acc);
            acc = fdot2u(t3.y, wv[p][3].y, acc);
            acc = fdot2u(t3.z, wv[p][3].z, acc);
            acc = fdot2u(t3.w, wv[p][3].w, acc);
            acc = DPPMOV(acc, 0x39);   // quad_perm [1,2,3,0]: dst q <- src q+1
        }
        // kh-reduce: sum stride-4 lane class {l, l+4, l+8, l+12} of the 16-row
        acc = DPPADD(acc, 0x124);      // row_ror:4
        acc = DPPADD(acc, 0x128);      // row_ror:8

        const float xp = (t & 1) ? xpB : xpA;
        const float h  = fast_tanh(acc + xp + bj);

        // publish h_t (this IS the kernel output row): agent-visible stores
        if (kh == 0)
            __hip_atomic_store((int*)(outb + (size_t)t * H_ + jg),
                               __builtin_bit_cast(int, h),
                               __ATOMIC_RELAXED, __HIP_MEMORY_SCOPE_AGENT);
        // xp prefetch t+2 (own chunk rows are written only by self, 2 steps
        // later; t>=S_-2 reads land in next batch / tail region, discarded)
        {
            float nxt = outb[(size_t)(t + 2) * H_ + jg];
            if (t & 1) xpB = nxt; else xpA = nxt;
        }
        if (t == S_ - 1 && kh == 0)
            out[(size_t)B_ * S_ * H_ + b * H_ + jg] = h;

        __syncthreads();               // all lanes' stores drained (vmcnt(0))
        if (tid == 60)
            __hip_atomic_store(&flags[b * 4 + c], t + 1,
                               __ATOMIC_RELEASE, __HIP_MEMORY_SCOPE_AGENT);
        if (t == S_ - 1) break;

        if (tid < 3) {                 // 3 lanes spin on the 3 peer chunks
            const int pp = (c + 1 + tid) & 3;
            while (__hip_atomic_load(&flags[b * 4 + pp], __ATOMIC_ACQUIRE,
                                     __HIP_MEMORY_SCOPE_AGENT) < t + 1)
                __builtin_amdgcn_s_sleep(1);
        }
        __syncthreads();               // peers' rows ready

        // --- stage h_t into buffer (t+1)&1 ---
        unsigned int* hd = hw + ((t + 1) & 1) * 256;
        float hq = DPPMOV(h, 0xB1);    // neighbor jlo^1's h
        if (kh == 0 && (jlo & 1) == 0)
            hd[swz(jg >> 1)] = pk2(h, hq);          // own 64 words
        if (tid < 192) {                            // peers' 192 words
            int w  = tid + (tid >= c * 64 ? 64 : 0);
            int i0 = __hip_atomic_load((const int*)(outb + (size_t)t * H_ + 2 * w),
                                       __ATOMIC_RELAXED, __HIP_MEMORY_SCOPE_AGENT);
            int i1 = __hip_atomic_load((const int*)(outb + (size_t)t * H_ + 2 * w + 1),
                                       __ATOMIC_RELAXED, __HIP_MEMORY_SCOPE_AGENT);
            hd[swz(w)] = pk2(__builtin_bit_cast(float, i0),
                             __builtin_bit_cast(float, i1));
        }
        __syncthreads();               // staging visible for next step
    }
}

extern "C" void kernel_launch(void* const* d_in, const int* in_sizes, int n_in,
                              void* d_out, int out_size, void* d_ws, size_t ws_size,
                              hipStream_t stream) {
    const float* inputs = (const float*)d_in[0];
    const float* h0     = (const float*)d_in[1];
    const float* W_ih   = (const float*)d_in[2];
    const float* W_hh   = (const float*)d_in[3];
    const float* b_ih   = (const float*)d_in[4];
    const float* b_hh   = (const float*)d_in[5];
    float* out = (float*)d_out;
    int* flags = (int*)d_ws;

    // 0) zero the 256 cross-WG step flags (every launch / graph replay)
    hipLaunchKernelGGL(zero_flags, dim3(1), dim3(256), 0, stream, flags);
    // 1) xp = inputs @ W_ih^T + b_ih  -> staged into d_out
    hipLaunchKernelGGL(xproj_gemm, dim3(131072 / 64), dim3(256), 0, stream,
                       inputs, W_ih, b_ih, out);
    // 2) sequential scan: 4 WGs per batch, h exchanged through `out` + flags
    hipLaunchKernelGGL(rnn_scan4, dim3(256), dim3(512), 0, stream,
                       h0, W_hh, b_hh, out, flags);
}

// Round 4
// 5950.338 us; speedup vs baseline: 2.1365x; 2.1365x over previous
//
#include <hip/hip_runtime.h>

#define B_ 64
#define S_ 2048
#define I_ 512
#define H_ 512

typedef _Float16 half2v __attribute__((ext_vector_type(2)));
typedef _Float16 half8v __attribute__((ext_vector_type(8)));
typedef float    float4v __attribute__((ext_vector_type(4)));
typedef unsigned int uint4v __attribute__((ext_vector_type(4)));

__device__ inline unsigned int pk2(float a, float b) {
    // v_cvt_pkrtz_f16_f32: pack (a->low, b->high)
    return __builtin_bit_cast(unsigned int, __builtin_amdgcn_cvt_pkrtz(a, b));
}

__device__ inline uint4v pack8(float4v a, float4v b) {
    uint4v r;
    r.x = pk2(a.x, a.y);
    r.y = pk2(a.z, a.w);
    r.z = pk2(b.x, b.y);
    r.w = pk2(b.z, b.w);
    return r;
}

__device__ inline float fdot2u(unsigned int h2, unsigned int w2, float acc) {
    return __builtin_amdgcn_fdot2(__builtin_bit_cast(half2v, h2),
                                  __builtin_bit_cast(half2v, w2), acc, false);
}

__device__ inline float fast_tanh(float y) {
    // tanh(y) = 1 - 2/(exp2(y*2*log2e) + 1); saturates correctly at +/-inf
    float e = __builtin_amdgcn_exp2f(y * 2.88539008f);
    return 1.f - 2.f * __builtin_amdgcn_rcpf(e + 1.f);
}

// pure DPP move (cross-lane permute), ctrl literal.
// 0x121 = row_ror:1 (rotate within 16-lane row), 0xB1 = quad_perm [1,0,3,2]
#define DPPMOVF(v, ctrl)                                                      \
    (__builtin_bit_cast(float, __builtin_amdgcn_update_dpp(                   \
        0, __builtin_bit_cast(int, (v)), (ctrl), 0xf, 0xf, true)))

// ---------------------------------------------------------------------------
// Kernel 1: xp[m, n] = sum_k inputs[m, k] * W_ih[n, k] + b_ih[n]
// M = 131072, N = 512, K = 512.  Unchanged (verified, ~470 us).
// ---------------------------------------------------------------------------
__global__ __launch_bounds__(256, 2) void xproj_gemm(
    const float* __restrict__ A,    // [131072, 512] inputs
    const float* __restrict__ Bw,   // [512, 512]    W_ih
    const float* __restrict__ bias, // [512]         b_ih
    float* __restrict__ C)          // [131072, 512] -> d_out
{
    __shared__ uint4v As[64 * 5];
    __shared__ uint4v Bs[512 * 5];

    const int tid  = threadIdx.x;
    const int wave = tid >> 6;
    const int lane = tid & 63;
    const int lm   = lane & 15;
    const int lq   = lane >> 4;
    const int m0   = blockIdx.x * 64;
    const int nb   = wave * 128;

    float4v acc[4][8];
#pragma unroll
    for (int mf = 0; mf < 4; ++mf)
#pragma unroll
        for (int nf = 0; nf < 8; ++nf)
            acc[mf][nf] = (float4v){0.f, 0.f, 0.f, 0.f};

    float biasv[8];
#pragma unroll
    for (int nf = 0; nf < 8; ++nf)
        biasv[nf] = bias[nb + nf * 16 + lm];

    const int sm    = tid >> 2;
    const int skq   = tid & 3;
    const int sslot = skq ^ (sm & 3);

    for (int kt = 0; kt < 16; ++kt) {
        const int k0 = kt * 32;
        const float* ap = A + (size_t)(m0 + sm) * 512 + k0 + skq * 8;
        float4v a0 = *(const float4v*)ap;
        float4v a1 = *(const float4v*)(ap + 4);
        float4v b0[8], b1[8];
#pragma unroll
        for (int i = 0; i < 8; ++i) {
            const float* bp = Bw + (size_t)(sm + 64 * i) * 512 + k0 + skq * 8;
            b0[i] = *(const float4v*)bp;
            b1[i] = *(const float4v*)(bp + 4);
        }
        __syncthreads();
        As[sm * 5 + sslot] = pack8(a0, a1);
#pragma unroll
        for (int i = 0; i < 8; ++i)
            Bs[(sm + 64 * i) * 5 + sslot] = pack8(b0[i], b1[i]);
        __syncthreads();

        half8v af[4];
#pragma unroll
        for (int mf = 0; mf < 4; ++mf) {
            int row = mf * 16 + lm;
            af[mf] = __builtin_bit_cast(half8v, As[row * 5 + (lq ^ (lm & 3))]);
        }
        half8v bfr[8];
#pragma unroll
        for (int nf = 0; nf < 8; ++nf) {
            int row = nb + nf * 16 + lm;
            bfr[nf] = __builtin_bit_cast(half8v, Bs[row * 5 + (lq ^ (lm & 3))]);
        }
#pragma unroll
        for (int mf = 0; mf < 4; ++mf)
#pragma unroll
            for (int nf = 0; nf < 8; ++nf)
                acc[mf][nf] = __builtin_amdgcn_mfma_f32_16x16x32_f16(
                    af[mf], bfr[nf], acc[mf][nf], 0, 0, 0);
    }

#pragma unroll
    for (int mf = 0; mf < 4; ++mf) {
        int mrow = m0 + mf * 16 + lq * 4;
#pragma unroll
        for (int nf = 0; nf < 8; ++nf) {
            float* cp = C + (size_t)mrow * 512 + nb + nf * 16 + lm;
            float4v v = acc[mf][nf];
            cp[0]    = v.x + biasv[nf];
            cp[512]  = v.y + biasv[nf];
            cp[1024] = v.z + biasv[nf];
            cp[1536] = v.w + biasv[nf];
        }
    }
}

// ---------------------------------------------------------------------------
// Kernel 2 (AGPR-PINNED W, take 2): one WG of 512 threads per batch, 64 WGs.
//
// Round-3 post-mortem: __launch_bounds__(512,2) empirically caps waves at
// 128 VGPRs on this toolchain (2nd arg acts as min BLOCKS/CU: 16 waves/CU
// -> 512-reg SIMD pool / 4 = 128) -> 192 hard "a"-constrained AGPRs were
// unallocatable -> deterministic backend failure. Fix: (512,1) (cap >= 256
// under either documented semantics; 1 block/CU is the wanted occupancy)
// and per-phase LDS-W reads (peak arch pressure -48 regs).
//
// Residency: 192 W pairs/thread pinned in AGPRs (384 KB/CU of the 512 KB
// unified file) + 4 phases of W in 128 KB LDS (slot-major: each wave's
// ds_read_b128 hits 64 consecutive 16B blocks = conflict-free floor).
// Decomposition: lane l = r*16+lam; 16-lane row owns j in [jb, jb+16),
// jb = w8*64 + r*16; lane lam holds h k-pairs [lam*16, lam*16+16) (4x b128,
// 4-way broadcast + 2-way banks = free tier). 16 phases x 16 fdot2; the
// accumulator rotates through the row via row_ror:1 after each phase; after
// 16 rotations acc is home (thread tid owns j = tid). Rotate DIRECTION is
// probed at runtime (1 instr) and the W row assignment flips to match.
// One barrier/step; h fp16 in a 2x1KB LDS double buffer.
// ---------------------------------------------------------------------------
__global__ __launch_bounds__(512, 1) void rnn_scan_agpr(
    const float* __restrict__ h0,   // [64, 512]
    const float* __restrict__ Whh,  // [512, 512]
    const float* __restrict__ bhh,  // [512]
    float* __restrict__ out)        // [B*S*H + B*H]
{
    __shared__ unsigned int hbuf[2][256];  // packed fp16 h, double-buffered
    __shared__ uint4v wlds[16 * 8 * 64];   // W phases 12..15, slot-major, 128 KB

    const int tid = threadIdx.x;
    const int l   = tid & 63;
    const int w8  = tid >> 6;      // wave 0..7
    const int lam = l & 15;        // k-lane within 16-row
    const int r   = l >> 4;        // row within wave
    const int b   = blockIdx.x;
    const int jb  = w8 * 64 + r * 16;   // row-group j base; own j = jb+lam = tid

    // --- probe DPP row_ror:1 direction; make W row assignment match it ---
    // Value-motion sigma(i)=i-1 (dst reads src i+1): phase p at lane lam
    // accumulates j = jb + ((lam + p) & 15)  -> sgn = 1; else sgn = 15.
    int rv = __builtin_amdgcn_update_dpp(0, lam, 0x121, 0xf, 0xf, true);
    const int sgn = (rv == ((lam + 15) & 15)) ? 15 : 1;

    // --- W AGPR part: phases 0..11, 192 packed pairs pinned in AGPRs ---
    unsigned int wa[192];
#pragma unroll
    for (int p = 0; p < 12; ++p) {
        const float* wr =
            Whh + (size_t)(jb + ((lam + sgn * p) & 15)) * 512 + 32 * lam;
#pragma unroll
        for (int uu = 0; uu < 8; ++uu) {
            float4v f = *(const float4v*)(wr + 4 * uu);
            unsigned int v0 = pk2(f.x, f.y);
            unsigned int v1 = pk2(f.z, f.w);
            asm volatile("v_accvgpr_write_b32 %0, %1"
                         : "=a"(wa[p * 16 + 2 * uu]) : "v"(v0));
            asm volatile("v_accvgpr_write_b32 %0, %1"
                         : "=a"(wa[p * 16 + 2 * uu + 1]) : "v"(v1));
        }
    }

    // --- W LDS part: phases 12..15, slot-major (conflict-free b128 reads) ---
#pragma unroll
    for (int q = 0; q < 4; ++q) {
        const float* wr =
            Whh + (size_t)(jb + ((lam + sgn * (12 + q)) & 15)) * 512 + 32 * lam;
#pragma unroll
        for (int i = 0; i < 4; ++i) {
            float4v f0 = *(const float4v*)(wr + 8 * i);
            float4v f1 = *(const float4v*)(wr + 8 * i + 4);
            wlds[((q * 4 + i) * 8 + w8) * 64 + l] = pack8(f0, f1);
        }
    }

    // --- stage h0 into hbuf[0]: pair k2 at word i4*64 + (k2>>4)*4 + (k2&3),
    //     i4=(k2>>2)&3. Read side: lane lam's b128 #i4 = bytes [i4*256+16lam)
    //     -> 4-way broadcast, 2-way banks: free tier. ---
    if (tid < 256) {
        int k2 = tid;
        float f0 = h0[b * 512 + 2 * k2];
        float f1 = h0[b * 512 + 2 * k2 + 1];
        hbuf[0][((k2 >> 2) & 3) * 64 + (k2 >> 4) * 4 + (k2 & 3)] = pk2(f0, f1);
    }

    const float bj = bhh[tid];
    float* outb = out + (size_t)b * (S_ * H_);
    float xpA = outb[tid];          // xp t=0
    float xpB = outb[H_ + tid];     // xp t=1
    __syncthreads();

    for (int t = 0; t < S_; ++t) {
        // own h slice: 4x b128, issued first (latency under AGPR phases)
        const uint4v* hb4 = (const uint4v*)&hbuf[t & 1][0];
        uint4v h4[4];
#pragma unroll
        for (int i4 = 0; i4 < 4; ++i4)
            h4[i4] = hb4[i4 * 16 + lam];

        float acc = 0.f;
        // phases 0..11: W from AGPRs (1 accvgpr_read + 1 fdot2 per pair)
#pragma unroll
        for (int p = 0; p < 12; ++p) {
#pragma unroll
            for (int u = 0; u < 16; ++u) {
                unsigned int wt;
                asm volatile("v_accvgpr_read_b32 %0, %1"
                             : "=v"(wt) : "a"(wa[p * 16 + u]));
                acc = fdot2u(h4[u >> 2][u & 3], wt, acc);
            }
            acc = DPPMOVF(acc, 0x121);   // rotate acc through the 16-row
        }
        // phases 12..15: W from LDS, loaded per-phase (16 transient regs;
        // load-use latency covered by the 2-waves/SIMD interleave)
#pragma unroll
        for (int q = 0; q < 4; ++q) {
            uint4v wq[4];
#pragma unroll
            for (int i = 0; i < 4; ++i)
                wq[i] = wlds[((q * 4 + i) * 8 + w8) * 64 + l];
#pragma unroll
            for (int u = 0; u < 16; ++u)
                acc = fdot2u(h4[u >> 2][u & 3], wq[u >> 2][u & 3], acc);
            acc = DPPMOVF(acc, 0x121);
        }
        // 16 rotations done: acc is home, thread tid owns j = tid.

        const float xp = (t & 1) ? xpB : xpA;
        const float h  = fast_tanh(acc + xp + bj);

        outb[(size_t)t * H_ + tid] = h;          // coalesced output row
        // stage h_t for next step: even tid packs (h_tid, h_tid+1)
        float hq = DPPMOVF(h, 0xB1);             // lane l^1's h (quad_perm)
        if ((tid & 1) == 0) {
            int k2 = tid >> 1;
            hbuf[(t + 1) & 1][((k2 >> 2) & 3) * 64 + (k2 >> 4) * 4 + (k2 & 3)] =
                pk2(h, hq);
        }
        // xp prefetch t+2 (t>=S_-2 lands in next batch / h_final tail:
        // in-bounds, value discarded)
        float nxt = outb[(size_t)(t + 2) * H_ + tid];
        if (t & 1) xpB = nxt; else xpA = nxt;
        if (t == S_ - 1)
            out[(size_t)B_ * S_ * H_ + b * H_ + tid] = h;

        __syncthreads();   // staged h visible before next step's reads
    }
}

extern "C" void kernel_launch(void* const* d_in, const int* in_sizes, int n_in,
                              void* d_out, int out_size, void* d_ws, size_t ws_size,
                              hipStream_t stream) {
    const float* inputs = (const float*)d_in[0];
    const float* h0     = (const float*)d_in[1];
    const float* W_ih   = (const float*)d_in[2];
    const float* W_hh   = (const float*)d_in[3];
    const float* b_ih   = (const float*)d_in[4];
    const float* b_hh   = (const float*)d_in[5];
    float* out = (float*)d_out;
    (void)d_ws; (void)ws_size;

    // 1) xp = inputs @ W_ih^T + b_ih  -> staged into d_out
    hipLaunchKernelGGL(xproj_gemm, dim3(131072 / 64), dim3(256), 0, stream,
                       inputs, W_ih, b_ih, out);
    // 2) sequential scan: 1 WG/batch, W pinned in AGPR (384KB) + LDS (128KB)
    hipLaunchKernelGGL(rnn_scan_agpr, dim3(B_), dim3(512), 0, stream,
                       h0, W_hh, b_hh, out);
}